// Round 1
// 589.048 us; speedup vs baseline: 1.2859x; 1.2859x over previous
//
#include <hip/hip_runtime.h>

// Swin window attention, fused one-kernel-per-window design.
// Shapes: B=64, RES=56, DIMS=192, HEADS=6, HD=32, WS=7, N=49, nW=64, SHIFT=3.
// Block = 768 threads (12 waves) = 1 window. All intermediates in LDS (bf16).
// 12-way work split (R1): LDS caps us at 1 block/CU (132 KB), so widen the
// block to 12 waves = 3 waves/SIMD for latency hiding (was 4 waves = 1/SIMD,
// Occupancy 11.7%). Phase splits divide evenly: QKV 36 col-tiles -> 3/wave
// (one matrix per wave group); attn 4 row-tiles x 3 head-pairs; out-proj
// 4 row-tiles x 3 col-groups.
//
// Layout facts used (verified per guide):
//   A-frag: lane holds A[m=lane&15][k=(lane>>4)*8 + j], j=0..7 (16B contig)
//   B-frag: lane holds B[k=(lane>>4)*8 + j][n=lane&15]
//   C/D   : lane holds D[m=(lane>>4)*4 + r][n=lane&15], r=0..3
// Weights pre-transposed to wT[n][k] bf16 so B-frags are contiguous 16B reads.
// V stored transposed (VT[n][k]) so PV B-frags are contiguous.
// Mask quirk: reference repeats mask by batch (scores[b*64+w] gets mask[b]).

typedef __attribute__((ext_vector_type(8))) short bf16x8;
typedef __attribute__((ext_vector_type(4))) short short4v;
typedef __attribute__((ext_vector_type(4))) float f32x4;

__device__ __forceinline__ short f2bf(float x) {
  unsigned u = __builtin_bit_cast(unsigned, x);
  u += 0x7fffu + ((u >> 16) & 1u);   // RNE
  return (short)(u >> 16);
}

// ---------------- prep: weight transpose->bf16, bias expansion ----------------
__global__ void prep_kernel(const float* __restrict__ wq, const float* __restrict__ wk,
                            const float* __restrict__ wv, const float* __restrict__ wo,
                            const float* __restrict__ table,
                            short* __restrict__ wT, float* __restrict__ biasx) {
  int tid = blockIdx.x * 256 + threadIdx.x;
  if (tid < 4 * 36864) {
    int mat = tid / 36864, rem = tid % 36864;
    int k = rem / 192, n = rem % 192;
    const float* w = (mat == 0) ? wq : (mat == 1) ? wk : (mat == 2) ? wv : wo;
    wT[mat * 36864 + n * 192 + k] = f2bf(w[k * 192 + n]);
  }
  if (tid < 6 * 2401) {
    int h = tid / 2401, rem = tid % 2401;
    int q = rem / 49, k = rem % 49;
    int idx = ((q / 7) - (k / 7) + 6) * 13 + ((q % 7) - (k % 7) + 6);
    biasx[tid] = table[idx * 6 + h];
  }
}

// ---------------- main fused kernel ----------------
__launch_bounds__(768, 3)
__global__ void swin_attn_kernel(const float* __restrict__ x,
                                 const short* __restrict__ wT,
                                 const float* __restrict__ biasx,
                                 const float* __restrict__ bq, const float* __restrict__ bk,
                                 const float* __restrict__ bv, const float* __restrict__ bo,
                                 float* __restrict__ out) {
  extern __shared__ short smem[];
  short* s_xw = smem;           // 64 x 200 (stride-padded), reused as O after phase 2
  short* s_q  = smem + 12800;   // 64 x 200
  short* s_k  = smem + 25600;   // 64 x 200
  short* s_vt = smem + 38400;   // 192 x 72  (V transposed: [col][row])
  short* s_p  = smem + 52224;   // 12 waves x 16 x 72 (private P strips)
  // total = 66048 shorts = 132096 B  (<= 160 KB, 1 block/CU by design)

  const int tid  = threadIdx.x;
  const int w    = tid >> 6;       // wave id 0..11
  const int lane = tid & 63;
  const int quad = lane >> 4;
  const int l15  = lane & 15;

  const int bw  = blockIdx.x;
  const int b   = bw >> 6;          // batch
  const int wi  = bw & 63;          // window in image
  const int wwh = wi >> 3, www = wi & 7;   // spatial window coords
  const int mwh = b >> 3,  mww = b & 7;    // mask window coords (reference quirk!)

  // ---- phase 1: load shifted window x -> LDS bf16 ----
  for (int i = tid; i < 49 * 48; i += 768) {
    int t = i / 48, c4 = i - t * 48;
    int th = t / 7, tw = t - th * 7;
    int gh = wwh * 7 + th + 3; if (gh >= 56) gh -= 56;
    int gw = www * 7 + tw + 3; if (gw >= 56) gw -= 56;
    const float4 v = *(const float4*)(x + (((b * 56 + gh) * 56 + gw) * 192 + c4 * 4));
    short4v s;
    ((short*)&s)[0] = f2bf(v.x); ((short*)&s)[1] = f2bf(v.y);
    ((short*)&s)[2] = f2bf(v.z); ((short*)&s)[3] = f2bf(v.w);
    *(short4v*)(s_xw + t * 200 + c4 * 4) = s;
  }
  __syncthreads();

  const f32x4 zero4 = {0.f, 0.f, 0.f, 0.f};

  // ---- phase 2: QKV projections ----
  // wave w: matrix mat = w>>2 (0=Q,1=K,2=V), col-tiles {(w&3)*3 + i}, i=0..2.
  {
    const int mat = w >> 2;
    const short* wt = wT + mat * 36864;
    const float* bias = (mat == 0) ? bq : (mat == 1) ? bk : bv;

    bf16x8 axw[4][6];
#pragma unroll
    for (int mt = 0; mt < 4; ++mt)
#pragma unroll
      for (int ks = 0; ks < 6; ++ks)
        axw[mt][ks] = *(const bf16x8*)(s_xw + (mt * 16 + l15) * 200 + ks * 32 + quad * 8);

#pragma unroll
    for (int i = 0; i < 3; ++i) {
      const int col = ((w & 3) * 3 + i) * 16 + l15;
      f32x4 acc[4] = {zero4, zero4, zero4, zero4};
#pragma unroll
      for (int ks = 0; ks < 6; ++ks) {
        bf16x8 bfr = *(const bf16x8*)(wt + col * 192 + ks * 32 + quad * 8);
#pragma unroll
        for (int mt = 0; mt < 4; ++mt)
          acc[mt] = __builtin_amdgcn_mfma_f32_16x16x32_bf16(axw[mt][ks], bfr, acc[mt], 0, 0, 0);
      }
      const float bv_ = bias[col];
      if (mat < 2) {
        short* dst = (mat == 0) ? s_q : s_k;
#pragma unroll
        for (int mt = 0; mt < 4; ++mt)
#pragma unroll
          for (int r = 0; r < 4; ++r)
            dst[(mt * 16 + quad * 4 + r) * 200 + col] = f2bf(acc[mt][r] + bv_);
      } else {
        // V stored transposed; zero pad rows >= 49 (required: P pad cols are 0,
        // and 0*NaN would poison valid outputs otherwise).
#pragma unroll
        for (int mt = 0; mt < 4; ++mt) {
          short4v vv;
#pragma unroll
          for (int r = 0; r < 4; ++r) {
            int m = mt * 16 + quad * 4 + r;
            float val = (m < 49) ? (acc[mt][r] + bv_) : 0.f;
            ((short*)&vv)[r] = f2bf(val);
          }
          *(short4v*)(s_vt + col * 72 + mt * 16 + quad * 4) = vv;
        }
      }
    }
  }
  __syncthreads();

  // ---- phase 3: attention ----
  // wave w: row-tile rt = w&3 (query rows 16rt..16rt+15), head-pair hp = w>>2
  // (heads 2hp, 2hp+1). P strip is wave-private; O cols [64hp,64hp+64) x rows
  // [16rt,16rt+16) are disjoint across waves.
  const int rt = w & 3;
  const int hp = w >> 2;

  int cm[4], mclamp[4];
#pragma unroll
  for (int r = 0; r < 4; ++r) {
    int m = rt * 16 + quad * 4 + r;
    int mm = (m < 49) ? m : 48;
    mclamp[r] = mm * 49;
    int th = mm / 7, tw = mm - th * 7;
    int ch = (mwh == 7) ? (1 + (th >= 4)) : 0;
    int cw = (mww == 7) ? (1 + (tw >= 4)) : 0;
    cm[r] = ch * 3 + cw;
  }
  int cn[4], nclamp[4], nvalid[4];
#pragma unroll
  for (int nt = 0; nt < 4; ++nt) {
    int n = nt * 16 + l15;
    nvalid[nt] = (n < 49);
    int nn = nvalid[nt] ? n : 48;
    nclamp[nt] = nn;
    int th = nn / 7, tw = nn - th * 7;
    int ch = (mwh == 7) ? (1 + (th >= 4)) : 0;
    int cw = (mww == 7) ? (1 + (tw >= 4)) : 0;
    cn[nt] = ch * 3 + cw;
  }

  short* my_p = s_p + w * (16 * 72);
  const float SCALE = 0.17677669529663687f;  // 1/sqrt(32)
  const float NEGINF = -__builtin_inff();

#pragma unroll
  for (int hh = 0; hh < 2; ++hh) {
    const int h = hp * 2 + hh;
    const int d0 = h * 32;
    bf16x8 qf = *(const bf16x8*)(s_q + (rt * 16 + l15) * 200 + d0 + quad * 8);
    float sv[4][4];
#pragma unroll
    for (int nt = 0; nt < 4; ++nt) {
      bf16x8 kf = *(const bf16x8*)(s_k + (nt * 16 + l15) * 200 + d0 + quad * 8);
      f32x4 sfr = __builtin_amdgcn_mfma_f32_16x16x32_bf16(qf, kf, zero4, 0, 0, 0);
#pragma unroll
      for (int r = 0; r < 4; ++r) {
        float v = sfr[r] * SCALE + biasx[h * 2401 + mclamp[r] + nclamp[nt]]
                + ((cm[r] == cn[nt]) ? 0.f : -1000.f);
        sv[nt][r] = nvalid[nt] ? v : NEGINF;
      }
    }
    // row softmax: row elements live across nt (4 frags) x 16 lanes of the quad
    float inv[4];
#pragma unroll
    for (int r = 0; r < 4; ++r) {
      float mx = fmaxf(fmaxf(sv[0][r], sv[1][r]), fmaxf(sv[2][r], sv[3][r]));
#pragma unroll
      for (int d = 1; d < 16; d <<= 1) mx = fmaxf(mx, __shfl_xor(mx, d));
      float s0 = 0.f;
#pragma unroll
      for (int nt = 0; nt < 4; ++nt) {
        float e = __expf(sv[nt][r] - mx);
        sv[nt][r] = e;
        s0 += e;
      }
#pragma unroll
      for (int d = 1; d < 16; d <<= 1) s0 += __shfl_xor(s0, d);
      inv[r] = 1.0f / s0;   // normalization folded into O epilogue
    }
    // write unnormalized P (bf16). Same-wave LDS RAW: DS ops in wave order, no barrier.
#pragma unroll
    for (int nt = 0; nt < 4; ++nt)
#pragma unroll
      for (int r = 0; r < 4; ++r)
        my_p[(quad * 4 + r) * 72 + nt * 16 + l15] = f2bf(sv[nt][r]);

    f32x4 of[2] = {zero4, zero4};
#pragma unroll
    for (int ks = 0; ks < 2; ++ks) {
      bf16x8 pf = *(const bf16x8*)(my_p + l15 * 72 + ks * 32 + quad * 8);
#pragma unroll
      for (int nt2 = 0; nt2 < 2; ++nt2) {
        bf16x8 vf = *(const bf16x8*)(s_vt + (d0 + nt2 * 16 + l15) * 72 + ks * 32 + quad * 8);
        of[nt2] = __builtin_amdgcn_mfma_f32_16x16x32_bf16(pf, vf, of[nt2], 0, 0, 0);
      }
    }
    // O -> LDS (s_xw reused), normalized
#pragma unroll
    for (int nt2 = 0; nt2 < 2; ++nt2)
#pragma unroll
      for (int r = 0; r < 4; ++r)
        s_xw[(rt * 16 + quad * 4 + r) * 200 + d0 + nt2 * 16 + l15] = f2bf(of[nt2][r] * inv[r]);
  }
  __syncthreads();

  // ---- phase 4: output projection + windowed store ----
  // wave w: rows of row-tile rt, col-tiles {cg*4 .. cg*4+3}, cg = w>>2.
  const int cg = hp;

  bf16x8 ao[6];
#pragma unroll
  for (int ks = 0; ks < 6; ++ks)
    ao[ks] = *(const bf16x8*)(s_xw + (rt * 16 + l15) * 200 + ks * 32 + quad * 8);

  int rowbase[4], rvalid[4];
#pragma unroll
  for (int r = 0; r < 4; ++r) {
    int m = rt * 16 + quad * 4 + r;
    rvalid[r] = (m < 49);
    int mm = rvalid[r] ? m : 0;
    int th = mm / 7, tw = mm - th * 7;
    int gh = wwh * 7 + th + 3; if (gh >= 56) gh -= 56;
    int gw = www * 7 + tw + 3; if (gw >= 56) gw -= 56;
    rowbase[r] = ((b * 56 + gh) * 56 + gw) * 192;
  }

  const short* wto = wT + 3 * 36864;
#pragma unroll
  for (int i = 0; i < 4; ++i) {
    const int col = (cg * 4 + i) * 16 + l15;
    f32x4 acc = zero4;
#pragma unroll
    for (int ks = 0; ks < 6; ++ks) {
      bf16x8 bfr = *(const bf16x8*)(wto + col * 192 + ks * 32 + quad * 8);
      acc = __builtin_amdgcn_mfma_f32_16x16x32_bf16(ao[ks], bfr, acc, 0, 0, 0);
    }
    const float bo_ = bo[col];
#pragma unroll
    for (int r = 0; r < 4; ++r)
      if (rvalid[r]) out[rowbase[r] + col] = acc[r] + bo_;
  }
}

extern "C" void kernel_launch(void* const* d_in, const int* in_sizes, int n_in,
                              void* d_out, int out_size, void* d_ws, size_t ws_size,
                              hipStream_t stream) {
  const float* x     = (const float*)d_in[0];
  const float* table = (const float*)d_in[1];
  const float* wq    = (const float*)d_in[2];
  const float* bq    = (const float*)d_in[3];
  const float* wk    = (const float*)d_in[4];
  const float* bk    = (const float*)d_in[5];
  const float* wv    = (const float*)d_in[6];
  const float* bv    = (const float*)d_in[7];
  const float* wo    = (const float*)d_in[8];
  const float* bo    = (const float*)d_in[9];
  float* out = (float*)d_out;

  short* wT    = (short*)d_ws;                       // 294912 B
  float* biasx = (float*)((char*)d_ws + 294912);     // 57624 B

  prep_kernel<<<576, 256, 0, stream>>>(wq, wk, wv, wo, table, wT, biasx);

  const int smem_bytes = 66048 * 2;  // 132096
  (void)hipFuncSetAttribute(reinterpret_cast<const void*>(swin_attn_kernel),
                            hipFuncAttributeMaxDynamicSharedMemorySize, smem_bytes);
  swin_attn_kernel<<<4096, 768, smem_bytes, stream>>>(x, wT, biasx, bq, bk, bv, bo, out);
}